// Round 16
// baseline (95.766 us; speedup 1.0000x reference)
//
#include <hip/hip_runtime.h>
#include <math.h>

#define BATCH 8
#define CH 320
#define HW 4096

typedef unsigned short u16;
typedef __attribute__((ext_vector_type(8))) short bf16x8;
typedef __attribute__((ext_vector_type(8))) unsigned short u16x8;
typedef __attribute__((ext_vector_type(4))) float f32x4;
typedef __attribute__((ext_vector_type(4))) float float4v;

// ws byte layout
#define ZP_OFF 0                 // 1 KB zero page (gload_lds OOB target)
#define SAMP_OFF 788480          // bf16 [b][4096][320] = 20,971,520 B
#define WT_OFF 21760000          // bf16 [chunk][tap][co][32] = 1,843,200 B
#define DESC_OFF 23603200        // uint4 [b][3][4096] = 1,572,864 B

// k_conv LDS layout
#define IBUF_BYTES 17408
#define A_OFF (2*IBUF_BYTES)         // 34816
#define APHASE 61440                 // 3 taps x 320co x 32ci x 2B
#define LDS_TOTAL (A_OFF + 2*APHASE) // 157696 B (<= 160 KiB)

__device__ __forceinline__ u16 f2bf(float f) {
    union { float f; unsigned u; } v; v.f = f;
    unsigned r = v.u + 0x7fffu + ((v.u >> 16) & 1u);   // RNE
    return (u16)(r >> 16);
}
__device__ __forceinline__ float bf2f(u16 h) {
    union { unsigned u; float f; } v; v.u = ((unsigned)h) << 16;
    return v.f;
}
__device__ __forceinline__ float bitf(unsigned u) {
    union { unsigned u; float f; } v; v.u = u; return v.f;
}
__device__ __forceinline__ void gl_lds16(const void* g, void* l) {
    __builtin_amdgcn_global_load_lds(
        (const __attribute__((address_space(1))) unsigned*)g,
        (__attribute__((address_space(3))) unsigned*)l, 16, 0, 0);
}

__device__ __forceinline__ void rodrigues3(float rv0, float rv1, float rv2, float* R) {
    float theta = sqrtf(rv0*rv0 + rv1*rv1 + rv2*rv2);
    float it = 1.0f / fmaxf(theta, 1e-12f);
    float r0 = rv0*it, r1 = rv1*it, r2 = rv2*it;
    float c = cosf(theta), s = sinf(theta), o = 1.0f - c;
    R[0]=c+o*r0*r0;    R[1]=o*r0*r1-s*r2; R[2]=o*r0*r2+s*r1;
    R[3]=o*r1*r0+s*r2; R[4]=c+o*r1*r1;    R[5]=o*r1*r2-s*r0;
    R[6]=o*r2*r0-s*r1; R[7]=o*r2*r1+s*r0; R[8]=c+o*r2*r2;
    if (theta < 1e-6f) { R[0]=1;R[1]=0;R[2]=0;R[3]=0;R[4]=1;R[5]=0;R[6]=0;R[7]=0;R[8]=1; }
}

__device__ __forceinline__ void inv3(const float* M, float* o) {
    float a=M[0],b=M[1],c=M[2],d=M[3],e=M[4],f=M[5],g=M[6],h=M[7],i=M[8];
    float A = e*i - f*h, B = f*g - d*i, C = d*h - e*g;
    float id = 1.0f / (a*A + b*B + c*C);
    o[0]=A*id;         o[1]=(c*h-b*i)*id; o[2]=(b*f-c*e)*id;
    o[3]=B*id;         o[4]=(a*i-c*g)*id; o[5]=(c*d-a*f)*id;
    o[6]=C*id;         o[7]=(b*g-a*h)*id; o[8]=(a*e-b*d)*id;
}

// fundamental matrix for batch b (computed redundantly per thread)
__device__ void compute_F(const float* Ks, const float* Kt, const float* ps,
                          const float* pt, int b, float* Fm) {
    float Rs[9], Rt[9];
    rodrigues3(ps[b*6+0], ps[b*6+1], ps[b*6+2], Rs);
    rodrigues3(pt[b*6+0], pt[b*6+1], pt[b*6+2], Rt);
    float Rr[9];
    #pragma unroll
    for (int i = 0; i < 3; ++i)
      #pragma unroll
      for (int k = 0; k < 3; ++k)
        Rr[i*3+k] = Rs[i*3+0]*Rt[k*3+0] + Rs[i*3+1]*Rt[k*3+1] + Rs[i*3+2]*Rt[k*3+2];
    float tt0 = pt[b*6+3], tt1 = pt[b*6+4], tt2 = pt[b*6+5];
    float tr0 = ps[b*6+3] - (Rr[0]*tt0 + Rr[1]*tt1 + Rr[2]*tt2);
    float tr1 = ps[b*6+4] - (Rr[3]*tt0 + Rr[4]*tt1 + Rr[5]*tt2);
    float tr2 = ps[b*6+5] - (Rr[6]*tt0 + Rr[7]*tt1 + Rr[8]*tt2);
    float E[9];
    #pragma unroll
    for (int j = 0; j < 3; ++j) {
        E[0*3+j] = -tr2*Rr[1*3+j] + tr1*Rr[2*3+j];
        E[1*3+j] =  tr2*Rr[0*3+j] - tr0*Rr[2*3+j];
        E[2*3+j] = -tr1*Rr[0*3+j] + tr0*Rr[1*3+j];
    }
    float iKs[9], iKt[9];
    inv3(Ks + b*9, iKs);
    inv3(Kt + b*9, iKt);
    float T[9];
    #pragma unroll
    for (int i = 0; i < 3; ++i)
      #pragma unroll
      for (int k = 0; k < 3; ++k)
        T[i*3+k] = iKt[0*3+i]*E[0*3+k] + iKt[1*3+i]*E[1*3+k] + iKt[2*3+i]*E[2*3+k];
    #pragma unroll
    for (int i = 0; i < 3; ++i)
      #pragma unroll
      for (int l = 0; l < 3; ++l)
        Fm[i*3 + l] = T[i*3+0]*iKs[0*3+l] + T[i*3+1]*iKs[1*3+l] + T[i*3+2]*iKs[2*3+l];
}

// LDS pixel-plane index swizzle (u16 units): bijective, keeps 16B granules
// intact, spreads writes/gathers over all bank groups. Max byte off 65408 -> u16.
#define PLIDX(p) (((p)<<3) ^ (((p)&0x70)>>1))

// per-pixel sample descriptors: for each of 3 samples pack 4 pre-swizzled LDS
// byte offsets (u16) + 4 bilinear weights (bf16) into one uint4.
// Also folds weight-prep (OIHW f32 -> [chunk][tap][co][32] bf16) + zero page.
__global__ __launch_bounds__(512) void k_coords(const float* __restrict__ Ks,
                                                const float* __restrict__ Kt,
                                                const float* __restrict__ ps,
                                                const float* __restrict__ pt,
                                                const float* __restrict__ wsrc,
                                                u16* __restrict__ wt,
                                                float* __restrict__ zp,
                                                uint4* __restrict__ desc) {
    int b = blockIdx.y;
    int k = blockIdx.x*512 + threadIdx.x;      // pixel
    int gid = (b*8 + blockIdx.x)*512 + threadIdx.x;   // 0..32767

    // folded weight prep
    for (int e = gid; e < 9*CH*CH; e += 32768) {
        int cl = e & 31;
        int r  = e >> 5;
        int co = r % CH;
        int q  = r / CH;
        int t  = q % 9;
        int cc = q / 9;
        int ci = cc*32 + cl;
        wt[e] = f2bf(wsrc[((size_t)co*CH + ci)*9 + t]);
    }
    if (gid < 256) zp[gid] = 0.0f;

    float Fm[9];
    compute_F(Ks, Kt, ps, pt, b, Fm);
    const float EPS = 1e-10f, W1 = 63.0f, H1 = 63.0f;
    float px = (float)(k & 63);
    float py = (float)(k >> 6);
    float a  = Fm[0]*px + Fm[3]*py + Fm[6];
    float bb = Fm[1]*px + Fm[4]*py + Fm[7];
    float c  = Fm[2]*px + Fm[5]*py + Fm[8];
    float x1 = fminf(fmaxf(-c/(a+EPS), 0.0f), W1);
    float x2 = fminf(fmaxf(-(bb*H1+c)/(a+EPS), 0.0f), W1);
    float y1 = fminf(fmaxf(-c/(bb+EPS), 0.0f), H1);
    float y2 = fminf(fmaxf(-(a*W1+c)/(bb+EPS), 0.0f), H1);
    float sxs[3], sys[3];
    sxs[0] = x1; sys[0] = y1;
    sxs[1] = 0.5f*(x1+x2); sys[1] = 0.5f*(y1+y2);
    sxs[2] = x2; sys[2] = y2;
    #pragma unroll
    for (int s = 0; s < 3; ++s) {
        float sx = sxs[s], sy = sys[s];
        float fx = floorf(sx), fy = floorf(sy);
        float wx = sx-fx, wy = sy-fy;
        int x0 = (int)fx, y0 = (int)fy;
        int x1i = min(x0+1,63), y1i = min(y0+1,63);
        unsigned o00 = (unsigned)PLIDX(y0*64+x0)  * 2u;
        unsigned o10 = (unsigned)PLIDX(y0*64+x1i) * 2u;
        unsigned o01 = (unsigned)PLIDX(y1i*64+x0) * 2u;
        unsigned o11 = (unsigned)PLIDX(y1i*64+x1i)* 2u;
        float w00=(1.f-wx)*(1.f-wy), w10=wx*(1.f-wy), w01=(1.f-wx)*wy, w11=wx*wy;
        uint4 d;
        d.x = o00 | (o10 << 16);
        d.y = o01 | (o11 << 16);
        d.z = (unsigned)f2bf(w00) | ((unsigned)f2bf(w10) << 16);
        d.w = (unsigned)f2bf(w01) | ((unsigned)f2bf(w11) << 16);
        desc[((size_t)b*3 + s)*HW + k] = d;
    }
}

// bilinear sampler: pure gather + FMA using precomputed descriptors.
// 8 channels/block, 512 threads; output channel-last bf16 [b][pix][320].
__global__ __launch_bounds__(512) void k_sample8(const float* __restrict__ x,
                                                 const uint4* __restrict__ desc,
                                                 u16* __restrict__ st) {
    __shared__ u16 pl[HW*8];   // 64 KB, swizzled [pix][8ch] bf16
    int cg = blockIdx.x, b = blockIdx.y;
    int tid = threadIdx.x;

    const float* xb = x + ((size_t)b*CH + cg*8)*HW;
    const float4v* xb4 = (const float4v*)xb;
    #pragma unroll
    for (int it = 0; it < 2; ++it) {
        int i0 = (it*512 + tid)*4;
        float4v v[8];
        #pragma unroll
        for (int c = 0; c < 8; ++c) v[c] = xb4[c*(HW/4) + it*512 + tid];
        #pragma unroll
        for (int j = 0; j < 4; ++j) {
            u16x8 o;
            #pragma unroll
            for (int c = 0; c < 8; ++c) o[c] = f2bf(v[c][j]);
            int pix = i0 + j;
            *(u16x8*)(pl + PLIDX(pix)) = o;
        }
    }
    __syncthreads();
    const char* pb = (const char*)pl;
    const uint4* db = desc + (size_t)b*3*HW;
    for (int k = tid; k < HW; k += 512) {
        float acc[8];
        #pragma unroll
        for (int c2 = 0; c2 < 8; ++c2) acc[c2] = 0.f;
        #pragma unroll
        for (int s = 0; s < 3; ++s) {
            uint4 d = db[s*HW + k];
            u16x8 g00 = *(const u16x8*)(pb + (d.x & 0xffffu));
            u16x8 g10 = *(const u16x8*)(pb + (d.x >> 16));
            u16x8 g01 = *(const u16x8*)(pb + (d.y & 0xffffu));
            u16x8 g11 = *(const u16x8*)(pb + (d.y >> 16));
            float w00 = bitf(d.z << 16), w10 = bitf(d.z & 0xffff0000u);
            float w01 = bitf(d.w << 16), w11 = bitf(d.w & 0xffff0000u);
            #pragma unroll
            for (int c2 = 0; c2 < 8; ++c2)
                acc[c2] += w00*bf2f(g00[c2]) + w10*bf2f(g10[c2])
                         + w01*bf2f(g01[c2]) + w11*bf2f(g11[c2]);
        }
        u16x8 o;
        #pragma unroll
        for (int c2 = 0; c2 < 8; ++c2) o[c2] = f2bf(acc[c2]*(1.f/3.f));
        *(u16x8*)(st + ((size_t)b*HW + k)*CH + cg*8) = o;
    }
}

// implicit-GEMM conv, A(weights) staged in LDS — r9/r13 structure, frozen
// (58.8us / MfmaUtil 41%, triple-reproduced; r10/r12/r14 variants all lost).
// Block = 512 thr (8 waves) = 320co x 128pix (2 rows); grid 256 = 1 block/CU.
// 30 phases (10 ci-chunks x 3 ky); single draining __syncthreads per phase.
__global__ __launch_bounds__(512, 1) void k_conv(const u16* __restrict__ st,
                                                 const u16* __restrict__ wt,
                                                 const float* __restrict__ bias,
                                                 const float* __restrict__ zp,
                                                 float* __restrict__ out) {
    __shared__ __align__(16) char lds[LDS_TOTAL];
    int rowblk = blockIdx.x;      // 0..31
    int b      = blockIdx.y;
    int y0 = rowblk*2;
    int lane = threadIdx.x & 63;
    int w = threadIdx.x >> 6;     // 0..7
    int wrow = w & 1;
    int co0w = (w >> 1) * 80;
    int l15 = lane & 15, l4 = lane >> 4;

    const u16* ga[3];
    int js[3];
    #pragma unroll
    for (int s = 0; s < 3; ++s) {
        int j = (s < 2) ? (s*8 + w) : 16;
        js[s] = j;
        int g = j*64 + lane;
        int row_l = g/264;
        int rem = g - row_l*264;
        int col = rem >> 2;
        int slot = rem & 3;
        int ks = slot ^ ((col>>1)&3);
        int yy = y0 - 1 + row_l;
        int xx = col - 1;
        bool oob = (g >= 1056) | (yy < 0) | (yy > 63) | (xx < 0) | (xx > 63);
        int yc = min(max(yy,0),63), xc = min(max(xx,0),63);
        const u16* p = st + (((size_t)b*HW) + yc*64 + xc)*CH + ks*8;
        ga[s] = oob ? (const u16*)zp : p;
    }
    int nslot = (w == 0) ? 3 : 2;

    int alaneoff = ((lane>>2)<<6) + ((((lane&3) ^ ((lane>>3)&3))) << 4);
    const char* asrc = (const char*)wt + alaneoff;

    int ard_off = (co0w + l15)*64 + ((l4 ^ ((l15>>1)&3)) << 4);

    f32x4 acc[5][4];
    #pragma unroll
    for (int mr = 0; mr < 5; ++mr)
        #pragma unroll
        for (int nf = 0; nf < 4; ++nf) acc[mr][nf] = (f32x4){0.f,0.f,0.f,0.f};

    #pragma unroll
    for (int s = 0; s < 3; ++s)
        if (s < nslot) gl_lds16(ga[s], lds + js[s]*1024);
    #pragma unroll
    for (int s = 0; s < 3; ++s) ga[s] += 32;
    #pragma unroll
    for (int s = 0; s < 8; ++s) {
        int j = s*8 + w;
        if (j < 60) gl_lds16(asrc + j*1024, lds + A_OFF + j*1024);
    }
    asrc += APHASE;
    __syncthreads();

    for (int c = 0; c < 10; ++c) {
        const char* ibuf = lds + (c&1)*IBUF_BYTES;
        #pragma unroll
        for (int ky = 0; ky < 3; ++ky) {
            int p = c*3 + ky;
            if (p < 29) {
                char* adst = lds + A_OFF + ((p+1)&1)*APHASE;
                #pragma unroll
                for (int s = 0; s < 8; ++s) {
                    int j = s*8 + w;
                    if (j < 60) gl_lds16(asrc + j*1024, adst + j*1024);
                }
                asrc += APHASE;
            }
            if (ky == 0 && c < 9) {
                char* idst = lds + ((c&1)^1)*IBUF_BYTES;
                #pragma unroll
                for (int s = 0; s < 3; ++s)
                    if (s < nslot) gl_lds16(ga[s], idst + js[s]*1024);
                #pragma unroll
                for (int s = 0; s < 3; ++s) ga[s] += 32;
            }
            const char* abuf = lds + A_OFF + (p&1)*APHASE;
            int rowbase = (wrow + ky) * 4224;
            #pragma unroll
            for (int kx = 0; kx < 3; ++kx) {
                bf16x8 bb[4];
                #pragma unroll
                for (int nf = 0; nf < 4; ++nf) {
                    int col = nf*16 + l15 + kx;
                    int boff = rowbase + col*64 + ((l4 ^ ((col>>1)&3))<<4);
                    bb[nf] = *(const bf16x8*)(ibuf + boff);
                }
                bf16x8 a[5];
                #pragma unroll
                for (int mr = 0; mr < 5; ++mr)
                    a[mr] = *(const bf16x8*)(abuf + kx*20480 + mr*1024 + ard_off);
                #pragma unroll
                for (int mr = 0; mr < 5; ++mr)
                    #pragma unroll
                    for (int nf = 0; nf < 4; ++nf)
                        acc[mr][nf] = __builtin_amdgcn_mfma_f32_16x16x32_bf16(
                            a[mr], bb[nf], acc[mr][nf], 0, 0, 0);
            }
            __syncthreads();
        }
    }

    int y = y0 + wrow;
    #pragma unroll
    for (int mr = 0; mr < 5; ++mr) {
        #pragma unroll
        for (int r = 0; r < 4; ++r) {
            int co = co0w + mr*16 + l4*4 + r;
            float bv = bias[co];
            float* ob = out + ((size_t)(b*CH + co))*HW + y*64;
            #pragma unroll
            for (int nf = 0; nf < 4; ++nf) {
                int xx = nf*16 + l15;
                ob[xx] = fmaxf(acc[mr][nf][r] + bv, 0.f);
            }
        }
    }
}

extern "C" void kernel_launch(void* const* d_in, const int* in_sizes, int n_in,
                              void* d_out, int out_size, void* d_ws, size_t ws_size,
                              hipStream_t stream) {
    const float* x  = (const float*)d_in[0];
    const float* Ks = (const float*)d_in[1];
    const float* Kt = (const float*)d_in[2];
    const float* ps = (const float*)d_in[3];
    const float* pt = (const float*)d_in[4];
    const float* cw = (const float*)d_in[5];
    const float* cb = (const float*)d_in[6];
    float* out = (float*)d_out;
    char* ws = (char*)d_ws;
    float* zp   = (float*)(ws + ZP_OFF);
    u16*   st   = (u16*)(ws + SAMP_OFF);
    u16*   wt   = (u16*)(ws + WT_OFF);
    uint4* desc = (uint4*)(ws + DESC_OFF);

    k_coords<<<dim3(HW/512, BATCH), 512, 0, stream>>>(Ks, Kt, ps, pt, cw, wt, zp, desc);
    k_sample8<<<dim3(CH/8, BATCH), 512, 0, stream>>>(x, desc, st);
    k_conv<<<dim3(32, BATCH), 512, 0, stream>>>(st, wt, cb, zp, out);
}

// Round 17
// 87.207 us; speedup vs baseline: 1.0981x; 1.0981x over previous
//
#include <hip/hip_runtime.h>
#include <math.h>

#define BATCH 8
#define CH 320
#define HW 4096

typedef unsigned short u16;
typedef __attribute__((ext_vector_type(8))) short bf16x8;
typedef __attribute__((ext_vector_type(8))) unsigned short u16x8;
typedef __attribute__((ext_vector_type(4))) float f32x4;
typedef __attribute__((ext_vector_type(4))) float float4v;

// ws byte layout
#define ZP_OFF 0                 // 1 KB zero page (gload_lds OOB target)
#define SAMP_OFF 788480          // bf16 [b][40cg][4096px][8ch] = 20,971,520 B
#define WT_OFF 21760000          // bf16 [chunk][tap][co][32] = 1,843,200 B

// k_conv LDS layout
#define IBUF_BYTES 17408
#define A_OFF (2*IBUF_BYTES)         // 34816
#define APHASE 61440                 // 3 taps x 320co x 32ci x 2B
#define LDS_TOTAL (A_OFF + 2*APHASE) // 157696 B (<= 160 KiB)

__device__ __forceinline__ u16 f2bf(float f) {
    union { float f; unsigned u; } v; v.f = f;
    unsigned r = v.u + 0x7fffu + ((v.u >> 16) & 1u);   // RNE
    return (u16)(r >> 16);
}
__device__ __forceinline__ float bf2f(u16 h) {
    union { unsigned u; float f; } v; v.u = ((unsigned)h) << 16;
    return v.f;
}
__device__ __forceinline__ void gl_lds16(const void* g, void* l) {
    __builtin_amdgcn_global_load_lds(
        (const __attribute__((address_space(1))) unsigned*)g,
        (__attribute__((address_space(3))) unsigned*)l, 16, 0, 0);
}

__device__ __forceinline__ void rodrigues3(float rv0, float rv1, float rv2, float* R) {
    float theta = sqrtf(rv0*rv0 + rv1*rv1 + rv2*rv2);
    float it = 1.0f / fmaxf(theta, 1e-12f);
    float r0 = rv0*it, r1 = rv1*it, r2 = rv2*it;
    float c = cosf(theta), s = sinf(theta), o = 1.0f - c;
    R[0]=c+o*r0*r0;    R[1]=o*r0*r1-s*r2; R[2]=o*r0*r2+s*r1;
    R[3]=o*r1*r0+s*r2; R[4]=c+o*r1*r1;    R[5]=o*r1*r2-s*r0;
    R[6]=o*r2*r0-s*r1; R[7]=o*r2*r1+s*r0; R[8]=c+o*r2*r2;
    if (theta < 1e-6f) { R[0]=1;R[1]=0;R[2]=0;R[3]=0;R[4]=1;R[5]=0;R[6]=0;R[7]=0;R[8]=1; }
}

__device__ __forceinline__ void inv3(const float* M, float* o) {
    float a=M[0],b=M[1],c=M[2],d=M[3],e=M[4],f=M[5],g=M[6],h=M[7],i=M[8];
    float A = e*i - f*h, B = f*g - d*i, C = d*h - e*g;
    float id = 1.0f / (a*A + b*B + c*C);
    o[0]=A*id;         o[1]=(c*h-b*i)*id; o[2]=(b*f-c*e)*id;
    o[3]=B*id;         o[4]=(a*i-c*g)*id; o[5]=(c*d-a*f)*id;
    o[6]=C*id;         o[7]=(b*g-a*h)*id; o[8]=(a*e-b*d)*id;
}

__device__ void compute_F(const float* Ks, const float* Kt, const float* ps,
                          const float* pt, int b, float* Fm) {
    float Rs[9], Rt[9];
    rodrigues3(ps[b*6+0], ps[b*6+1], ps[b*6+2], Rs);
    rodrigues3(pt[b*6+0], pt[b*6+1], pt[b*6+2], Rt);
    float Rr[9];
    #pragma unroll
    for (int i = 0; i < 3; ++i)
      #pragma unroll
      for (int k = 0; k < 3; ++k)
        Rr[i*3+k] = Rs[i*3+0]*Rt[k*3+0] + Rs[i*3+1]*Rt[k*3+1] + Rs[i*3+2]*Rt[k*3+2];
    float tt0 = pt[b*6+3], tt1 = pt[b*6+4], tt2 = pt[b*6+5];
    float tr0 = ps[b*6+3] - (Rr[0]*tt0 + Rr[1]*tt1 + Rr[2]*tt2);
    float tr1 = ps[b*6+4] - (Rr[3]*tt0 + Rr[4]*tt1 + Rr[5]*tt2);
    float tr2 = ps[b*6+5] - (Rr[6]*tt0 + Rr[7]*tt1 + Rr[8]*tt2);
    float E[9];
    #pragma unroll
    for (int j = 0; j < 3; ++j) {
        E[0*3+j] = -tr2*Rr[1*3+j] + tr1*Rr[2*3+j];
        E[1*3+j] =  tr2*Rr[0*3+j] - tr0*Rr[2*3+j];
        E[2*3+j] = -tr1*Rr[0*3+j] + tr0*Rr[1*3+j];
    }
    float iKs[9], iKt[9];
    inv3(Ks + b*9, iKs);
    inv3(Kt + b*9, iKt);
    float T[9];
    #pragma unroll
    for (int i = 0; i < 3; ++i)
      #pragma unroll
      for (int k = 0; k < 3; ++k)
        T[i*3+k] = iKt[0*3+i]*E[0*3+k] + iKt[1*3+i]*E[1*3+k] + iKt[2*3+i]*E[2*3+k];
    #pragma unroll
    for (int i = 0; i < 3; ++i)
      #pragma unroll
      for (int l = 0; l < 3; ++l)
        Fm[i*3 + l] = T[i*3+0]*iKs[0*3+l] + T[i*3+1]*iKs[1*3+l] + T[i*3+2]*iKs[2*3+l];
}

// LDS pixel-plane index swizzle (u16 units): bijective, keeps 16B granules
// intact, spreads writes/gathers over all bank groups.
#define PLIDX(p) (((p)<<3) ^ (((p)&0x70)>>1))

// fused: weight prep + zero page + fundamental matrix + epipolar lines +
// bilinear sample (3 pts, mean). 8 channels/block, 512 threads; output
// [b][cg][pix][8ch] -> each wave stores 1KB CONTIGUOUS (coalesced; the old
// [b][pix][320] layout amplified writes ~1.3x at 640B stride).
__global__ __launch_bounds__(512) void k_sample8(const float* __restrict__ x,
                                                 const float* __restrict__ Ks,
                                                 const float* __restrict__ Kt,
                                                 const float* __restrict__ ps,
                                                 const float* __restrict__ pt,
                                                 const float* __restrict__ wsrc,
                                                 u16* __restrict__ wt,
                                                 float* __restrict__ zp,
                                                 u16* __restrict__ st) {
    __shared__ u16 pl[HW*8];   // 64 KB, swizzled [pix][8ch] bf16
    int cg = blockIdx.x, b = blockIdx.y;
    int tid = threadIdx.x;
    int bid = b*40 + cg;   // 0..319

    // folded weight prep: OIHW f32 -> [chunk][tap][co][32] bf16
    for (int e = bid*512 + tid; e < 9*CH*CH; e += 320*512) {
        int cl = e & 31;
        int r  = e >> 5;
        int co = r % CH;
        int q  = r / CH;
        int t  = q % 9;
        int cc = q / 9;
        int ci = cc*32 + cl;
        wt[e] = f2bf(wsrc[((size_t)co*CH + ci)*9 + t]);
    }
    if (bid == 0 && tid < 256) zp[tid] = 0.0f;   // 1 KB zero page

    const float* xb = x + ((size_t)b*CH + cg*8)*HW;
    const float4v* xb4 = (const float4v*)xb;
    #pragma unroll
    for (int it = 0; it < 2; ++it) {
        int i0 = (it*512 + tid)*4;
        float4v v[8];
        #pragma unroll
        for (int c = 0; c < 8; ++c) v[c] = xb4[c*(HW/4) + it*512 + tid];
        #pragma unroll
        for (int j = 0; j < 4; ++j) {
            u16x8 o;
            #pragma unroll
            for (int c = 0; c < 8; ++c) o[c] = f2bf(v[c][j]);
            int pix = i0 + j;
            *(u16x8*)(pl + PLIDX(pix)) = o;
        }
    }
    float Fm[9];
    compute_F(Ks, Kt, ps, pt, b, Fm);
    __syncthreads();
    const float EPS = 1e-10f, W1 = 63.0f, H1 = 63.0f;
    u16* ob = st + ((size_t)bid)*HW*8;
    for (int k = tid; k < HW; k += 512) {
        float px = (float)(k & 63);
        float py = (float)(k >> 6);
        float a  = Fm[0]*px + Fm[3]*py + Fm[6];
        float bb = Fm[1]*px + Fm[4]*py + Fm[7];
        float c  = Fm[2]*px + Fm[5]*py + Fm[8];
        float x1 = fminf(fmaxf(-c/(a+EPS), 0.0f), W1);
        float x2 = fminf(fmaxf(-(bb*H1+c)/(a+EPS), 0.0f), W1);
        float y1 = fminf(fmaxf(-c/(bb+EPS), 0.0f), H1);
        float y2 = fminf(fmaxf(-(a*W1+c)/(bb+EPS), 0.0f), H1);
        float sxs[3], sys[3];
        sxs[0] = x1; sys[0] = y1;
        sxs[1] = 0.5f*(x1+x2); sys[1] = 0.5f*(y1+y2);
        sxs[2] = x2; sys[2] = y2;
        float acc[8];
        #pragma unroll
        for (int c2 = 0; c2 < 8; ++c2) acc[c2] = 0.f;
        #pragma unroll
        for (int s = 0; s < 3; ++s) {
            float sx = sxs[s], sy = sys[s];
            float fx = floorf(sx), fy = floorf(sy);
            float wx = sx-fx, wy = sy-fy;
            int x0 = (int)fx, y0 = (int)fy;
            int x1i = min(x0+1,63), y1i = min(y0+1,63);
            u16x8 g00 = *(const u16x8*)(pl + PLIDX(y0*64+x0));
            u16x8 g10 = *(const u16x8*)(pl + PLIDX(y0*64+x1i));
            u16x8 g01 = *(const u16x8*)(pl + PLIDX(y1i*64+x0));
            u16x8 g11 = *(const u16x8*)(pl + PLIDX(y1i*64+x1i));
            float w00=(1.f-wx)*(1.f-wy), w10=wx*(1.f-wy), w01=(1.f-wx)*wy, w11=wx*wy;
            #pragma unroll
            for (int c2 = 0; c2 < 8; ++c2)
                acc[c2] += w00*bf2f(g00[c2]) + w10*bf2f(g10[c2])
                         + w01*bf2f(g01[c2]) + w11*bf2f(g11[c2]);
        }
        u16x8 o;
        #pragma unroll
        for (int c2 = 0; c2 < 8; ++c2) o[c2] = f2bf(acc[c2]*(1.f/3.f));
        *(u16x8*)(ob + (size_t)k*8) = o;   // contiguous 16B/lane -> coalesced
    }
}

// implicit-GEMM conv, A(weights) staged in LDS — r9/r13 structure, frozen
// (58.8us / MfmaUtil ~42%, 4x reproduced; r10/r12/r14 restructures all lost).
// Block = 512 thr (8 waves) = 320co x 128pix; flat grid 256 with XCD swizzle:
// b = bid&7, rowblk = bid>>3 -> each XCD owns one batch; st[b] (2.6MB) and wt
// (1.8MB) stay XCD-L2-resident. st layout now [b][cg][pix][8].
__global__ __launch_bounds__(512, 1) void k_conv(const u16* __restrict__ st,
                                                 const u16* __restrict__ wt,
                                                 const float* __restrict__ bias,
                                                 const float* __restrict__ zp,
                                                 float* __restrict__ out) {
    __shared__ __align__(16) char lds[LDS_TOTAL];
    int bid = blockIdx.x;
    int b      = bid & 7;         // XCD-local batch (round-robin dispatch % 8)
    int rowblk = bid >> 3;        // 0..31
    int y0 = rowblk*2;
    int lane = threadIdx.x & 63;
    int w = threadIdx.x >> 6;     // 0..7
    int wrow = w & 1;
    int co0w = (w >> 1) * 80;
    int l15 = lane & 15, l4 = lane >> 4;

    // ---- input staging: 1056 granules over 17 insts; wave w: slots {w, 8+w},
    // wave 0 additionally slot 16 (granules >=1056 OOB -> zero page).
    // NEW global layout: granule (pix, ks) at st[((b*40 + c*4 + ks)*HW + pix)*8].
    const u16* ga[3];
    int js[3], stp[3];
    #pragma unroll
    for (int s = 0; s < 3; ++s) {
        int j = (s < 2) ? (s*8 + w) : 16;
        js[s] = j;
        int g = j*64 + lane;
        int row_l = g/264;
        int rem = g - row_l*264;
        int col = rem >> 2;
        int slot = rem & 3;
        int ks = slot ^ ((col>>1)&3);
        int yy = y0 - 1 + row_l;
        int xx = col - 1;
        bool oob = (g >= 1056) | (yy < 0) | (yy > 63) | (xx < 0) | (xx > 63);
        int yc = min(max(yy,0),63), xc = min(max(xx,0),63);
        const u16* p = st + (((size_t)b*40 + ks)*HW + (yc*64 + xc))*8;
        ga[s]  = oob ? (const u16*)zp : p;
        stp[s] = oob ? 0 : 4*HW*8;     // +4 cg-planes per ci-chunk
    }
    int nslot = (w == 0) ? 3 : 2;

    // ---- A staging: phase region = 61440B; inst j = s*8+w (j<60) covers 1024B.
    int alaneoff = ((lane>>2)<<6) + ((((lane&3) ^ ((lane>>3)&3))) << 4);
    const char* asrc = (const char*)wt + alaneoff;

    // ---- A read: byte = A_OFF + buf*APHASE + kx*20480 + mr*1024 + ard_off
    int ard_off = (co0w + l15)*64 + ((l4 ^ ((l15>>1)&3)) << 4);

    f32x4 acc[5][4];
    #pragma unroll
    for (int mr = 0; mr < 5; ++mr)
        #pragma unroll
        for (int nf = 0; nf < 4; ++nf) acc[mr][nf] = (f32x4){0.f,0.f,0.f,0.f};

    // ---- prologue: stage input chunk0 + A phase0
    #pragma unroll
    for (int s = 0; s < 3; ++s)
        if (s < nslot) gl_lds16(ga[s], lds + js[s]*1024);
    #pragma unroll
    for (int s = 0; s < 3; ++s) ga[s] += stp[s];
    #pragma unroll
    for (int s = 0; s < 8; ++s) {
        int j = s*8 + w;
        if (j < 60) gl_lds16(asrc + j*1024, lds + A_OFF + j*1024);
    }
    asrc += APHASE;
    __syncthreads();

    for (int c = 0; c < 10; ++c) {
        const char* ibuf = lds + (c&1)*IBUF_BYTES;
        #pragma unroll
        for (int ky = 0; ky < 3; ++ky) {
            int p = c*3 + ky;
            if (p < 29) {
                char* adst = lds + A_OFF + ((p+1)&1)*APHASE;
                #pragma unroll
                for (int s = 0; s < 8; ++s) {
                    int j = s*8 + w;
                    if (j < 60) gl_lds16(asrc + j*1024, adst + j*1024);
                }
                asrc += APHASE;
            }
            if (ky == 0 && c < 9) {
                char* idst = lds + ((c&1)^1)*IBUF_BYTES;
                #pragma unroll
                for (int s = 0; s < 3; ++s)
                    if (s < nslot) gl_lds16(ga[s], idst + js[s]*1024);
                #pragma unroll
                for (int s = 0; s < 3; ++s) ga[s] += stp[s];
            }
            const char* abuf = lds + A_OFF + (p&1)*APHASE;
            int rowbase = (wrow + ky) * 4224;
            #pragma unroll
            for (int kx = 0; kx < 3; ++kx) {
                bf16x8 bb[4];
                #pragma unroll
                for (int nf = 0; nf < 4; ++nf) {
                    int col = nf*16 + l15 + kx;
                    int boff = rowbase + col*64 + ((l4 ^ ((col>>1)&3))<<4);
                    bb[nf] = *(const bf16x8*)(ibuf + boff);
                }
                bf16x8 a[5];
                #pragma unroll
                for (int mr = 0; mr < 5; ++mr)
                    a[mr] = *(const bf16x8*)(abuf + kx*20480 + mr*1024 + ard_off);
                #pragma unroll
                for (int mr = 0; mr < 5; ++mr)
                    #pragma unroll
                    for (int nf = 0; nf < 4; ++nf)
                        acc[mr][nf] = __builtin_amdgcn_mfma_f32_16x16x32_bf16(
                            a[mr], bb[nf], acc[mr][nf], 0, 0, 0);
            }
            __syncthreads();
        }
    }

    int y = y0 + wrow;
    #pragma unroll
    for (int mr = 0; mr < 5; ++mr) {
        #pragma unroll
        for (int r = 0; r < 4; ++r) {
            int co = co0w + mr*16 + l4*4 + r;
            float bv = bias[co];
            float* ob = out + ((size_t)(b*CH + co))*HW + y*64;
            #pragma unroll
            for (int nf = 0; nf < 4; ++nf) {
                int xx = nf*16 + l15;
                ob[xx] = fmaxf(acc[mr][nf][r] + bv, 0.f);
            }
        }
    }
}

extern "C" void kernel_launch(void* const* d_in, const int* in_sizes, int n_in,
                              void* d_out, int out_size, void* d_ws, size_t ws_size,
                              hipStream_t stream) {
    const float* x  = (const float*)d_in[0];
    const float* Ks = (const float*)d_in[1];
    const float* Kt = (const float*)d_in[2];
    const float* ps = (const float*)d_in[3];
    const float* pt = (const float*)d_in[4];
    const float* cw = (const float*)d_in[5];
    const float* cb = (const float*)d_in[6];
    float* out = (float*)d_out;
    char* ws = (char*)d_ws;
    float* zp = (float*)(ws + ZP_OFF);
    u16*   st = (u16*)(ws + SAMP_OFF);
    u16*   wt = (u16*)(ws + WT_OFF);

    k_sample8<<<dim3(CH/8, BATCH), 512, 0, stream>>>(x, Ks, Kt, ps, pt, cw, wt, zp, st);
    k_conv<<<256, 512, 0, stream>>>(st, wt, cb, zp, out);
}